// Round 1
// baseline (504.793 us; speedup 1.0000x reference)
//
#include <hip/hip_runtime.h>
#include <hip/hip_bf16.h>

// Problem constants
constexpr int Bb = 4, Nn = 1024, Kk = 32;
constexpr int CS = 384, CZ = 128, CH = 16, Hh = 12, PQn = 4, PVn = 8;
constexpr int HC = Hh * CH;            // 192
constexpr int NCOLS = 1152;            // q(192)|k(192)|v(192)|qp(144)|kvp(432)
constexpr int FEAT = 960;              // o(192)|o_pt(288)|dists(96)|o_pair(384)
constexpr int NNODE = Bb * Nn;         // 4096
constexpr int NEDGE = NNODE * Kk;      // 131072

// Workspace float offsets (flag occupies wsf[0..3])
constexpr int O_WNODE = 4;                          // [384][1152] f32
constexpr int O_WZ    = O_WNODE + 384 * 1152;       // [128][44]  f32
constexpr int O_WOUT  = O_WZ + 128 * 44;            // [960][384] f32
constexpr int O_SLN   = O_WOUT + 960 * 384;         // [4096][384]
constexpr int O_P     = O_SLN + NNODE * CS;         // [4096][1152]
constexpr int O_BB    = O_P + NNODE * NCOLS;        // [131072][12]
constexpr int O_ZD    = O_BB + NEDGE * 12;          // [131072][32]
constexpr int O_FEAT  = O_ZD + NEDGE * 32;          // [4096][960]
constexpr int TOTAL_F = O_FEAT + NNODE * FEAT;      // ~16.8M floats = 67.2 MB

__device__ __forceinline__ float ldf(const float* p, int i) { return p[i]; }
__device__ __forceinline__ float ldf(const __hip_bfloat16* p, int i) { return __bfloat162float(p[i]); }
__device__ __forceinline__ void stf(float* p, int i, float v) { p[i] = v; }
__device__ __forceinline__ void stf(__hip_bfloat16* p, int i, float v) { p[i] = __float2bfloat16(v); }

// Detect input dtype from s_mask (all ones): f32 -> 0x3F800000, bf16x2 -> 0x3F803F80
__global__ void k_detect(const unsigned* smask_raw, int* flag) {
    if (threadIdx.x == 0) *flag = (smask_raw[0] == 0x3F803F80u) ? 1 : 0;
}

// Concat + convert weights to f32 in ws
template <typename T>
__global__ __launch_bounds__(256) void k_wconv(const T* wq, const T* wk, const T* wv,
                                               const T* wqp, const T* wkvp, const T* wb,
                                               const T* wdz, const T* wout, float* wsf,
                                               const int* flag, int want) {
    if (*flag != want) return;
    int idx = blockIdx.x * 256 + threadIdx.x;
    if (idx < 384 * 1152) {
        int row = idx / 1152, col = idx - row * 1152;
        float v;
        if      (col < 192) v = ldf(wq,  row * 192 + col);
        else if (col < 384) v = ldf(wk,  row * 192 + col - 192);
        else if (col < 576) v = ldf(wv,  row * 192 + col - 384);
        else if (col < 720) v = ldf(wqp, row * 144 + col - 576);
        else                v = ldf(wkvp, row * 432 + col - 720);
        wsf[O_WNODE + idx] = v;
    } else if (idx < 384 * 1152 + 128 * 44) {
        int u = idx - 384 * 1152;
        int row = u / 44, col = u - row * 44;
        float v = (col < 12) ? ldf(wb, row * 12 + col) : ldf(wdz, row * 32 + col - 12);
        wsf[O_WZ + u] = v;
    } else if (idx < 384 * 1152 + 128 * 44 + 960 * 384) {
        int u = idx - (384 * 1152 + 128 * 44);
        wsf[O_WOUT + u] = ldf(wout, u);
    }
}

// LayerNorm of s rows (384) -> f32
template <typename T>
__global__ __launch_bounds__(384) void k_sln(const T* s, const T* sc, const T* bi,
                                             float* sln, const int* flag, int want) {
    if (*flag != want) return;
    int row = blockIdx.x, t = threadIdx.x;
    float x = ldf(s, row * CS + t);
    float sum = x, sq = x * x;
    #pragma unroll
    for (int m = 32; m; m >>= 1) { sum += __shfl_xor(sum, m, 64); sq += __shfl_xor(sq, m, 64); }
    __shared__ float ssum[6], ssq[6];
    int w = t >> 6;
    if ((t & 63) == 0) { ssum[w] = sum; ssq[w] = sq; }
    __syncthreads();
    if (t == 0) {
        float S = 0, Q = 0;
        for (int i = 0; i < 6; i++) { S += ssum[i]; Q += ssq[i]; }
        ssum[0] = S; ssq[0] = Q;
    }
    __syncthreads();
    float mean = ssum[0] * (1.f / CS);
    float var  = ssq[0] * (1.f / CS) - mean * mean;
    float r = rsqrtf(var + 1e-5f);
    sln[row * CS + t] = (x - mean) * r * ldf(sc, t) + ldf(bi, t);
}

// z LayerNorm + [w_b | w_down_z] projection. 8 z-rows per 256-thread block.
template <typename T>
__global__ __launch_bounds__(256) void k_z(const T* z, const T* zsc, const T* zbi,
                                           const float* WzF, float* bbuf, float* zd,
                                           const int* flag, int want) {
    if (*flag != want) return;
    __shared__ float wz[128 * 44];
    __shared__ float zl[8][128];
    int t = threadIdx.x;
    for (int i = t; i < 128 * 44; i += 256) wz[i] = WzF[i];
    int r = t >> 5, lane = t & 31;
    int row = blockIdx.x * 8 + r;
    float x[4]; float sum = 0, sq = 0;
    #pragma unroll
    for (int j = 0; j < 4; j++) {
        float v = ldf(z, row * CZ + lane + 32 * j);
        x[j] = v; sum += v; sq += v * v;
    }
    #pragma unroll
    for (int m = 16; m; m >>= 1) { sum += __shfl_xor(sum, m, 64); sq += __shfl_xor(sq, m, 64); }
    float mean = sum * (1.f / CZ), var = sq * (1.f / CZ) - mean * mean;
    float rs = rsqrtf(var + 1e-5f);
    #pragma unroll
    for (int j = 0; j < 4; j++) {
        int c = lane + 32 * j;
        zl[r][c] = (x[j] - mean) * rs * ldf(zsc, c) + ldf(zbi, c);
    }
    __syncthreads();
    for (int o = lane; o < 44; o += 32) {
        float acc = 0;
        for (int c = 0; c < 128; c++) acc += zl[r][c] * wz[c * 44 + o];
        if (o < 12) bbuf[row * 12 + o] = acc;
        else        zd[row * 32 + (o - 12)] = acc;
    }
}

// Generic f32 tiled GEMM: C[M x cols] = A[M x Kdim] * B[Kdim x cols]; 64x64 tile / block.
template <typename TO>
__global__ __launch_bounds__(256) void k_gemm(const float* A, int lda, const float* Bm, int ldb,
                                              TO* C, int ldc, int Kdim, const int* flag, int want) {
    if (flag && *flag != want) return;
    __shared__ float As[16][68];
    __shared__ float Bs[16][64];
    int t = threadIdx.x;
    int row0 = blockIdx.x * 64, col0 = blockIdx.y * 64;
    int tx = t & 15, ty = t >> 4;
    int ar = t >> 2, aq = t & 3;
    int bc = t & 63, bk0 = t >> 6;
    float acc[4][4] = {};
    for (int kt = 0; kt < Kdim; kt += 16) {
        float4 av = *(const float4*)(A + (row0 + ar) * lda + kt + aq * 4);
        As[aq * 4 + 0][ar] = av.x; As[aq * 4 + 1][ar] = av.y;
        As[aq * 4 + 2][ar] = av.z; As[aq * 4 + 3][ar] = av.w;
        #pragma unroll
        for (int i = 0; i < 4; i++)
            Bs[bk0 + 4 * i][bc] = Bm[(kt + bk0 + 4 * i) * ldb + col0 + bc];
        __syncthreads();
        #pragma unroll
        for (int kk = 0; kk < 16; kk++) {
            float a0 = As[kk][ty * 4], a1 = As[kk][ty * 4 + 1], a2 = As[kk][ty * 4 + 2], a3 = As[kk][ty * 4 + 3];
            float b0 = Bs[kk][tx * 4], b1 = Bs[kk][tx * 4 + 1], b2 = Bs[kk][tx * 4 + 2], b3 = Bs[kk][tx * 4 + 3];
            acc[0][0] += a0 * b0; acc[0][1] += a0 * b1; acc[0][2] += a0 * b2; acc[0][3] += a0 * b3;
            acc[1][0] += a1 * b0; acc[1][1] += a1 * b1; acc[1][2] += a1 * b2; acc[1][3] += a1 * b3;
            acc[2][0] += a2 * b0; acc[2][1] += a2 * b1; acc[2][2] += a2 * b2; acc[2][3] += a2 * b3;
            acc[3][0] += a3 * b0; acc[3][1] += a3 * b1; acc[3][2] += a3 * b2; acc[3][3] += a3 * b3;
        }
        __syncthreads();
    }
    #pragma unroll
    for (int i = 0; i < 4; i++)
        #pragma unroll
        for (int j = 0; j < 4; j++)
            stf(C, (row0 + ty * 4 + i) * ldc + col0 + tx * 4 + j, acc[i][j]);
}

// Per-node attention: logits, softmax, o / o_pt / dists / o_pair -> feat
template <typename T>
__global__ __launch_bounds__(384) void k_attn(const float* P, const float* bbuf, const float* zd,
                                              const int* eidx, const T* smask, const T* rot,
                                              const T* hwq, float* featg, const int* flag, int want) {
    if (*flag != want) return;
    int node = blockIdx.x;
    int b = node >> 10;   // N = 1024
    int t = threadIdx.x;
    __shared__ float q_s[192], qp_s[144], hw_s[12], m_s[32], Mn[9];
    __shared__ int j_s[32];
    __shared__ float l_s[384];
    __shared__ float feat_s[960];
    const float* Pn = P + node * NCOLS;
    if (t < 192)       q_s[t] = Pn[t];
    else if (t < 336)  qp_s[t - 192] = Pn[576 + (t - 192)];
    else if (t < 368) {
        int k = t - 336;
        int j = eidx[node * Kk + k];
        j_s[k] = b * Nn + j;
        m_s[k] = ldf(smask, node) * ldf(smask, b * Nn + j);
    } else if (t < 380) {
        int h = t - 368;
        float x = ldf(hwq, h);
        hw_s[h] = logf(1.f + expf(x)) * 0.13608276348795434f;  // softplus * sqrt(1/54)
    }
    if (t < 9) {  // M = R^T R (captures bf16 non-orthonormality of rot)
        int i = t / 3, j = t - i * 3;
        float m = 0;
        #pragma unroll
        for (int l = 0; l < 3; l++)
            m += ldf(rot, node * 9 + l * 3 + i) * ldf(rot, node * 9 + l * 3 + j);
        Mn[t] = m;
    }
    __syncthreads();
    {   // logits + softmax; t = h*32 + k
        int h = t >> 5, k = t & 31;
        const float* Pj = P + j_s[k] * NCOLS;
        float qk = 0;
        #pragma unroll
        for (int c = 0; c < 16; c++) qk += q_s[h * 16 + c] * Pj[192 + h * 16 + c];
        float M00 = Mn[0], M01 = Mn[1], M02 = Mn[2], M11 = Mn[4], M12 = Mn[5], M22 = Mn[8];
        float sq = 0;
        #pragma unroll
        for (int p = 0; p < 4; p++) {
            float d0 = qp_s[(h * 4 + p) * 3 + 0] - Pj[720 + (h * 12 + p) * 3 + 0];
            float d1 = qp_s[(h * 4 + p) * 3 + 1] - Pj[720 + (h * 12 + p) * 3 + 1];
            float d2 = qp_s[(h * 4 + p) * 3 + 2] - Pj[720 + (h * 12 + p) * 3 + 2];
            sq += M00 * d0 * d0 + M11 * d1 * d1 + M22 * d2 * d2
                + 2.f * (M01 * d0 * d1 + M02 * d0 * d2 + M12 * d1 * d2);
        }
        float logit = qk * 0.14433756729740643f                     // 1/sqrt(48)
                    + 0.5773502691896258f * bbuf[(node * Kk + k) * 12 + h]
                    - 0.5f * hw_s[h] * sq
                    + 1e5f * (m_s[k] - 1.f);
        float mx = logit;
        #pragma unroll
        for (int m = 16; m; m >>= 1) mx = fmaxf(mx, __shfl_xor(mx, m, 64));
        float e = expf(logit - mx);
        float ssum = e;
        #pragma unroll
        for (int m = 16; m; m >>= 1) ssum += __shfl_xor(ssum, m, 64);
        l_s[t] = e / ssum;
    }
    __syncthreads();
    // 864 accumulation tasks: o(192) | o_pt raw(288) | o_pair(384)
    for (int task = t; task < 864; task += 384) {
        float acc = 0;
        if (task < 192) {
            int h = task >> 4, c = task & 15;
            for (int k = 0; k < 32; k++)
                acc += l_s[h * 32 + k] * P[j_s[k] * NCOLS + 384 + h * 16 + c];
            feat_s[task] = acc;
        } else if (task < 480) {
            int u = task - 192;
            int hv = u / 3, i = u - hv * 3;
            int h = hv >> 3, v = hv & 7;
            for (int k = 0; k < 32; k++)
                acc += l_s[h * 32 + k] * P[j_s[k] * NCOLS + 720 + (h * 12 + 4 + v) * 3 + i];
            feat_s[192 + u] = acc;   // raw (pre-M)
        } else {
            int u = task - 480;
            int h = u >> 5, c = u & 31;
            for (int k = 0; k < 32; k++)
                acc += l_s[h * 32 + k] * zd[(node * Kk + k) * 32 + c];
            feat_s[576 + u] = acc;
        }
    }
    __syncthreads();
    if (t < 96) {  // apply M to o_pt, compute dists
        float r0 = feat_s[192 + t * 3 + 0];
        float r1 = feat_s[192 + t * 3 + 1];
        float r2 = feat_s[192 + t * 3 + 2];
        float o0 = Mn[0] * r0 + Mn[1] * r1 + Mn[2] * r2;
        float o1 = Mn[3] * r0 + Mn[4] * r1 + Mn[5] * r2;
        float o2 = Mn[6] * r0 + Mn[7] * r1 + Mn[8] * r2;
        feat_s[192 + t * 3 + 0] = o0;
        feat_s[192 + t * 3 + 1] = o1;
        feat_s[192 + t * 3 + 2] = o2;
        feat_s[480 + t] = sqrtf(o0 * o0 + o1 * o1 + o2 * o2 + 1e-8f);
    }
    __syncthreads();
    for (int f = t; f < FEAT; f += 384) featg[node * FEAT + f] = feat_s[f];
}

extern "C" void kernel_launch(void* const* d_in, const int* in_sizes, int n_in,
                              void* d_out, int out_size, void* d_ws, size_t ws_size,
                              hipStream_t stream) {
    float* wsf = (float*)d_ws;
    int* flag = (int*)d_ws;
    const void* s = d_in[0];   const void* z = d_in[1];
    const int* eidx = (const int*)d_in[2];
    const void* rot = d_in[3];                         // d_in[4] trans: unused (cancels exactly)
    const void* smask = d_in[5];
    const void* lns_sc = d_in[6]; const void* lns_bi = d_in[7];
    const void* lnz_sc = d_in[8]; const void* lnz_bi = d_in[9];
    const void* wq = d_in[10]; const void* wk = d_in[11]; const void* wv = d_in[12];
    const void* wqp = d_in[13]; const void* wkvp = d_in[14];
    const void* wb = d_in[15]; const void* wdz = d_in[16];
    const void* hwq = d_in[17]; const void* wout = d_in[18];

    k_detect<<<1, 64, 0, stream>>>((const unsigned*)smask, flag);

    // dtype-guarded variants: want=0 (f32), want=1 (bf16)
    k_wconv<float><<<3190, 256, 0, stream>>>((const float*)wq, (const float*)wk, (const float*)wv,
        (const float*)wqp, (const float*)wkvp, (const float*)wb, (const float*)wdz,
        (const float*)wout, wsf, flag, 0);
    k_wconv<__hip_bfloat16><<<3190, 256, 0, stream>>>((const __hip_bfloat16*)wq, (const __hip_bfloat16*)wk,
        (const __hip_bfloat16*)wv, (const __hip_bfloat16*)wqp, (const __hip_bfloat16*)wkvp,
        (const __hip_bfloat16*)wb, (const __hip_bfloat16*)wdz, (const __hip_bfloat16*)wout, wsf, flag, 1);

    k_sln<float><<<NNODE, 384, 0, stream>>>((const float*)s, (const float*)lns_sc, (const float*)lns_bi,
                                            wsf + O_SLN, flag, 0);
    k_sln<__hip_bfloat16><<<NNODE, 384, 0, stream>>>((const __hip_bfloat16*)s, (const __hip_bfloat16*)lns_sc,
                                                     (const __hip_bfloat16*)lns_bi, wsf + O_SLN, flag, 1);

    k_z<float><<<NEDGE / 8, 256, 0, stream>>>((const float*)z, (const float*)lnz_sc, (const float*)lnz_bi,
                                              wsf + O_WZ, wsf + O_BB, wsf + O_ZD, flag, 0);
    k_z<__hip_bfloat16><<<NEDGE / 8, 256, 0, stream>>>((const __hip_bfloat16*)z, (const __hip_bfloat16*)lnz_sc,
                                                       (const __hip_bfloat16*)lnz_bi,
                                                       wsf + O_WZ, wsf + O_BB, wsf + O_ZD, flag, 1);

    // P = s_ln @ [w_q|w_k|w_v|w_q_pts|w_kv_pts]   (always f32, no guard)
    k_gemm<float><<<dim3(NNODE / 64, NCOLS / 64), 256, 0, stream>>>(
        wsf + O_SLN, CS, wsf + O_WNODE, NCOLS, wsf + O_P, NCOLS, CS, (const int*)nullptr, 0);

    k_attn<float><<<NNODE, 384, 0, stream>>>(wsf + O_P, wsf + O_BB, wsf + O_ZD, eidx,
        (const float*)smask, (const float*)rot, (const float*)hwq, wsf + O_FEAT, flag, 0);
    k_attn<__hip_bfloat16><<<NNODE, 384, 0, stream>>>(wsf + O_P, wsf + O_BB, wsf + O_ZD, eidx,
        (const __hip_bfloat16*)smask, (const __hip_bfloat16*)rot, (const __hip_bfloat16*)hwq,
        wsf + O_FEAT, flag, 1);

    // out = feat @ w_out
    k_gemm<float><<<dim3(NNODE / 64, CS / 64), 256, 0, stream>>>(
        wsf + O_FEAT, FEAT, wsf + O_WOUT, CS, (float*)d_out, CS, FEAT, flag, 0);
    k_gemm<__hip_bfloat16><<<dim3(NNODE / 64, CS / 64), 256, 0, stream>>>(
        wsf + O_FEAT, FEAT, wsf + O_WOUT, CS, (__hip_bfloat16*)d_out, CS, FEAT, flag, 1);
}